// Round 7
// baseline (266.664 us; speedup 1.0000x reference)
//
#include <hip/hip_runtime.h>
#include <hip/hip_bf16.h>
#include <stdint.h>

#define S 4096
#define HID 1024
#define NH 16
#define DH 64

typedef __attribute__((ext_vector_type(4))) short s16x4;
typedef __attribute__((ext_vector_type(8))) short short8;
typedef __attribute__((ext_vector_type(4))) float f32x4;
typedef __attribute__((ext_vector_type(16))) float f32x16;

__device__ __forceinline__ unsigned short f2bf(float f) {
  unsigned int u = __builtin_bit_cast(unsigned int, f);
  u += 0x7FFF + ((u >> 16) & 1);   // round-to-nearest-even
  return (unsigned short)(u >> 16);
}
// pack two fp32 -> bf16x2 dword by truncation (1 v_perm_b32)
__device__ __forceinline__ unsigned int pktrunc(float lo, float hi) {
  return __builtin_amdgcn_perm(__builtin_bit_cast(unsigned int, hi),
                               __builtin_bit_cast(unsigned int, lo), 0x07060302u);
}
// async global->LDS, 16B per lane
__device__ __forceinline__ void gload16(const unsigned short* g, unsigned short* l) {
  __builtin_amdgcn_global_load_lds((const __attribute__((address_space(1))) unsigned int*)g,
                                   (__attribute__((address_space(3))) unsigned int*)l, 16, 0, 0);
}

// ---------------------------------------------------------------- cast fp32 -> bf16
__global__ __launch_bounds__(256) void cast_kernel(
    const float* __restrict__ x,  const float* __restrict__ wq,
    const float* __restrict__ wk, const float* __restrict__ wv,
    const float* __restrict__ wo,
    unsigned short* __restrict__ xb,  unsigned short* __restrict__ wqb,
    unsigned short* __restrict__ wkb, unsigned short* __restrict__ wvb,
    unsigned short* __restrict__ wob)
{
  int y = blockIdx.y;
  const float* src; unsigned short* dst; int n;
  if      (y == 0) { src = x;  dst = xb;  n = S * HID; }
  else if (y == 1) { src = wq; dst = wqb; n = HID * HID; }
  else if (y == 2) { src = wk; dst = wkb; n = HID * HID; }
  else if (y == 3) { src = wv; dst = wvb; n = HID * HID; }
  else             { src = wo; dst = wob; n = HID * HID; }
  int i = (blockIdx.x * 256 + threadIdx.x) * 4;
  if (i < n) {
    float4 v = *reinterpret_cast<const float4*>(src + i);
    ushort4 o;
    o.x = f2bf(v.x); o.y = f2bf(v.y); o.z = f2bf(v.z); o.w = f2bf(v.w);
    *reinterpret_cast<ushort4*>(dst + i) = o;
  }
}

// ---------------------------------------------------------------- 128x128 NT GEMM core (m97-style)
__device__ __forceinline__ void gemm128(
    const unsigned short* __restrict__ A, const unsigned short* __restrict__ W,
    unsigned short* As, unsigned short* Bs, f32x4 acc[4][4], int row0, int col0)
{
  const int tid = threadIdx.x;
  const int wave = tid >> 6, lane = tid & 63, quad = lane >> 4, l16 = lane & 15;
  const int wr = (wave >> 1) * 64, wc = (wave & 1) * 64;
  const int srow = lane >> 2, sseg = lane & 3;
  const f32x4 z = {0.f, 0.f, 0.f, 0.f};
  #pragma unroll
  for (int i = 0; i < 4; i++)
    #pragma unroll
    for (int j = 0; j < 4; j++) acc[i][j] = z;

  for (int k0 = 0; k0 < HID; k0 += 32) {
    __syncthreads();
    #pragma unroll
    for (int c = 0; c < 2; c++) {
      const int rbase = c * 64 + wave * 16;
      gload16(A + (size_t)(row0 + rbase + srow) * HID + k0 + sseg * 8, As + rbase * 32);
      gload16(W + (size_t)(col0 + rbase + srow) * HID + k0 + sseg * 8, Bs + rbase * 32);
    }
    __syncthreads();

    short8 af[4], bfr[4];
    #pragma unroll
    for (int i = 0; i < 4; i++)
      af[i] = *reinterpret_cast<const short8*>(As + (wr + i * 16 + l16) * 32 + quad * 8);
    #pragma unroll
    for (int j = 0; j < 4; j++)
      bfr[j] = *reinterpret_cast<const short8*>(Bs + (wc + j * 16 + l16) * 32 + quad * 8);
    #pragma unroll
    for (int i = 0; i < 4; i++)
      #pragma unroll
      for (int j = 0; j < 4; j++)
        acc[i][j] = __builtin_amdgcn_mfma_f32_16x16x32_bf16(af[i], bfr[j], acc[i][j], 0, 0, 0);
  }
}

// QKV projections. Q -> [H][S][64] prescaled by log2e/8.
// K -> K2 frag-packed (K=16 A-op): K2[(((h*128+g)*4+c)*64 + lane)*8 + j]
//      lane=(hf*32+key&31), c=dh>>4, hf=(dh>>3)&1, j=dh&7, g=key>>5
// V -> Vb frag-packed (K=8 B-op):  Vb[((((h*512+kw)*2+ng)*2+hfb)*32 + (dh&31))*4 + j]
//      kw=key>>3, hfb=(key>>2)&1, j=key&3, ng=dh>>5
__global__ __launch_bounds__(256) void qkv_gemm_kernel(
    const unsigned short* __restrict__ X,
    const unsigned short* __restrict__ Wq, const unsigned short* __restrict__ Wk,
    const unsigned short* __restrict__ Wv,
    const float* __restrict__ bq, const float* __restrict__ bk, const float* __restrict__ bv,
    unsigned short* __restrict__ Qo, unsigned short* __restrict__ K2o, unsigned short* __restrict__ Vbo)
{
  __shared__ unsigned short As[128 * 32];
  __shared__ unsigned short Bs[128 * 32];
  const int zsel = blockIdx.z;
  const unsigned short* W = (zsel == 0) ? Wq : (zsel == 1) ? Wk : Wv;
  const float* bias        = (zsel == 0) ? bq : (zsel == 1) ? bk : bv;
  const int row0 = blockIdx.x * 128, col0 = blockIdx.y * 128;
  f32x4 acc[4][4];
  gemm128(X, W, As, Bs, acc, row0, col0);

  const int tid = threadIdx.x;
  const int wave = tid >> 6, lane = tid & 63, quad = lane >> 4, l16 = lane & 15;
  const int wr = (wave >> 1) * 64, wc = (wave & 1) * 64;

  if (zsel == 0) {
    const float osc = 0.18033688011112042f;   // log2(e)/8
    #pragma unroll
    for (int j = 0; j < 4; j++) {
      int n = col0 + wc + j * 16 + l16;
      float bb = bias[n];
      int h = n >> 6, d = n & 63;
      #pragma unroll
      for (int i = 0; i < 4; i++)
        #pragma unroll
        for (int rr = 0; rr < 4; rr++) {
          int s = row0 + wr + i * 16 + quad * 4 + rr;
          Qo[(size_t)(h * S + s) * DH + d] = f2bf((acc[i][j][rr] + bb) * osc);
        }
    }
  } else if (zsel == 1) {
    #pragma unroll
    for (int j = 0; j < 4; j++) {
      int n = col0 + wc + j * 16 + l16;
      float bb = bias[n];
      int h = n >> 6, dh = n & 63;
      int c = dh >> 4, hfk = (dh >> 3) & 1, j8 = dh & 7;
      #pragma unroll
      for (int i = 0; i < 4; i++)
        #pragma unroll
        for (int rr = 0; rr < 4; rr++) {
          int s = row0 + wr + i * 16 + quad * 4 + rr;
          int g = s >> 5, l32k = s & 31;
          K2o[((size_t)((h * 128 + g) * 4 + c) * 64 + hfk * 32 + l32k) * 8 + j8] =
              f2bf(acc[i][j][rr] + bb);
        }
    }
  } else {
    #pragma unroll
    for (int j = 0; j < 4; j++) {
      int n = col0 + wc + j * 16 + l16;
      float bb = bias[n];
      int h = n >> 6, dh = n & 63;
      int ng = dh >> 5, l32v = dh & 31;
      #pragma unroll
      for (int i = 0; i < 4; i++) {
        int sb = row0 + wr + i * 16 + quad * 4;   // rr = key&3 (sb multiple of 4)
        int kw = sb >> 3, hfb = (sb >> 2) & 1;
        ushort4 pv;
        pv.x = f2bf(acc[i][j][0] + bb); pv.y = f2bf(acc[i][j][1] + bb);
        pv.z = f2bf(acc[i][j][2] + bb); pv.w = f2bf(acc[i][j][3] + bb);
        *reinterpret_cast<ushort4*>(
            Vbo + ((size_t)(((h * 512 + kw) * 2 + ng) * 2 + hfb) * 32 + l32v) * 4) = pv;
      }
    }
  }
}

// out = A @ W^T + bias_eff
__global__ __launch_bounds__(256) void out_gemm_kernel(
    const unsigned short* __restrict__ A, const unsigned short* __restrict__ W,
    const float* __restrict__ be, float* __restrict__ dst)
{
  __shared__ unsigned short As[128 * 32];
  __shared__ unsigned short Bs[128 * 32];
  const int row0 = blockIdx.x * 128, col0 = blockIdx.y * 128;
  f32x4 acc[4][4];
  gemm128(A, W, As, Bs, acc, row0, col0);

  const int tid = threadIdx.x;
  const int wave = tid >> 6, lane = tid & 63, quad = lane >> 4, l16 = lane & 15;
  const int wr = (wave >> 1) * 64, wc = (wave & 1) * 64;
  #pragma unroll
  for (int j = 0; j < 4; j++) {
    int n = col0 + wc + j * 16 + l16;
    float bb = be[n];
    #pragma unroll
    for (int i = 0; i < 4; i++)
      #pragma unroll
      for (int rr = 0; rr < 4; rr++) {
        int s = row0 + wr + i * 16 + quad * 4 + rr;
        dst[(size_t)s * HID + n] = acc[i][j][rr] + bb;
      }
  }
}

// VsumP[p][h*64+d] = partial sum over kw range (two-stage, 128 blocks)
__global__ __launch_bounds__(256) void vsum_kernel(
    const unsigned short* __restrict__ Vb, float* __restrict__ VsumP)
{
  __shared__ float red[256];
  const int p = blockIdx.x, h = blockIdx.y, tid = threadIdx.x;
  const int d = tid & 63, chunk = tid >> 6;
  const int ng = d >> 5, l32 = d & 31;
  float s = 0.f;
  for (int m = 0; m < 16; m++) {
    int kw = p * 64 + chunk * 16 + m;
    #pragma unroll
    for (int hfb = 0; hfb < 2; hfb++) {
      uint2 u = *reinterpret_cast<const uint2*>(
          Vb + ((size_t)(((h * 512 + kw) * 2 + ng) * 2 + hfb) * 32 + l32) * 4);
      s += __builtin_bit_cast(float, u.x << 16);
      s += __builtin_bit_cast(float, u.x & 0xFFFF0000u);
      s += __builtin_bit_cast(float, u.y << 16);
      s += __builtin_bit_cast(float, u.y & 0xFFFF0000u);
    }
  }
  red[tid] = s;
  __syncthreads();
  if (tid < 64)
    VsumP[p * 1024 + h * 64 + tid] = red[tid] + red[64 + tid] + red[128 + tid] + red[192 + tid];
}

// be[n] = bo[n] + (Vsum . wo[n,:]) / 4097, Vsum = sum of 8 partials
__global__ __launch_bounds__(256) void biasfold_kernel(
    const float* __restrict__ VsumP, const float* __restrict__ wo,
    const float* __restrict__ bo, float* __restrict__ be)
{
  const int n = blockIdx.x * 4 + (threadIdx.x >> 6);
  const int l = threadIdx.x & 63;
  float acc = 0.f;
  #pragma unroll
  for (int i = 0; i < 16; i++) {
    float vs = 0.f;
    #pragma unroll
    for (int p = 0; p < 8; p++) vs += VsumP[p * 1024 + l + 64 * i];
    acc += vs * wo[(size_t)n * HID + l + 64 * i];
  }
  #pragma unroll
  for (int off = 32; off >= 1; off >>= 1) acc += __shfl_xor(acc, off);
  if (l == 0) be[n] = bo[n] + acc * (1.f / 4097.f);
}

// ---------------------------------------------------------------- attention v5
// Collapsed double softmax (w = 1+p): out = (Vsum + softmax1(S)V)/4097.
// PV via 32x32x8 MFMA: the S^T C-layout reg-quad IS a K=8 A-operand after
// exp+pack -> ZERO cross-lane ops in the loop (no LDS, no bpermute).
// Block = 64 q: waves (qc 0..1) x (ks 0..1); one barrier at the end.
__global__ __launch_bounds__(256, 4) void attn_kernel(
    const unsigned short* __restrict__ Q, const unsigned short* __restrict__ K2,
    const unsigned short* __restrict__ Vb, unsigned short* __restrict__ OUT)
{
  __shared__ float Ol[2][32][64];
  __shared__ float Z1l[128];

  const int h = blockIdx.y, q0 = blockIdx.x * 64;
  const int tid = threadIdx.x;
  const int wave = tid >> 6, lane = tid & 63, hf = lane >> 5, l32 = lane & 31;
  const int qc = wave & 1, ks = wave >> 1;

  // Q B-frags (K=16 QK): B[k=c*16+hf*8+j][n=q=l32]
  short8 qf[4];
  {
    const unsigned short* qrow = Q + (size_t)(h * S + q0 + qc * 32 + l32) * DH;
    #pragma unroll
    for (int c = 0; c < 4; c++)
      qf[c] = *reinterpret_cast<const short8*>(qrow + c * 16 + hf * 8);
  }

  float z1p = 0.f;
  f32x16 Oa[2];
  #pragma unroll
  for (int ng = 0; ng < 2; ng++)
    #pragma unroll
    for (int r = 0; r < 16; r++) Oa[ng][r] = 0.f;

  const int g0 = ks * 64, g1 = g0 + 64;
  for (int g = g0; g < g1; g++) {
    // K A-frags (coalesced dwordx4): A[m=key=l32][k=c*16+hf*8+j]
    short8 kf[4];
    #pragma unroll
    for (int c = 0; c < 4; c++)
      kf[c] = *reinterpret_cast<const short8*>(
          K2 + ((size_t)((h * 128 + g) * 4 + c) * 64 + lane) * 8);
    // V B-frags (K=8): B[k=hf*4+j][n=d=ng*32+l32] for key-window kw=4g+w2
    s16x4 vf[4][2];
    #pragma unroll
    for (int w2 = 0; w2 < 4; w2++)
      #pragma unroll
      for (int ng = 0; ng < 2; ng++)
        vf[w2][ng] = *reinterpret_cast<const s16x4*>(
            Vb + ((size_t)(((h * 512 + g * 4 + w2) * 2 + ng) * 2 + hf) * 32 + l32) * 4);

    // S^T tile: 32 keys x 32 q (C: col=q=l32, row=key=(reg&3)+4hf+8(reg>>2))
    f32x16 acc;
    #pragma unroll
    for (int r = 0; r < 16; r++) acc[r] = 0.f;
    #pragma unroll
    for (int c = 0; c < 4; c++)
      acc = __builtin_amdgcn_mfma_f32_32x32x16_bf16(kf[c], qf[c], acc, 0, 0, 0);

    // per reg-quad w2: keys 8*w2 + 4*hf + {0..3}  ==  K=8 A-operand layout
    #pragma unroll
    for (int w2 = 0; w2 < 4; w2++) {
      float t0 = __builtin_amdgcn_exp2f(acc[4 * w2 + 0]);
      float t1 = __builtin_amdgcn_exp2f(acc[4 * w2 + 1]);
      float t2 = __builtin_amdgcn_exp2f(acc[4 * w2 + 2]);
      float t3 = __builtin_amdgcn_exp2f(acc[4 * w2 + 3]);
      z1p += (t0 + t1) + (t2 + t3);
      uint2 pa; pa.x = pktrunc(t0, t1); pa.y = pktrunc(t2, t3);
      s16x4 A8 = __builtin_bit_cast(s16x4, pa);
      Oa[0] = __builtin_amdgcn_mfma_f32_32x32x8bf16_1k(A8, vf[w2][0], Oa[0], 0, 0, 0);
      Oa[1] = __builtin_amdgcn_mfma_f32_32x32x8bf16_1k(A8, vf[w2][1], Oa[1], 0, 0, 0);
    }
  }

  {
    float z1 = z1p + __shfl_xor(z1p, 32);
    if (hf == 0) Z1l[ks * 64 + qc * 32 + l32] = z1;
  }
  if (ks == 0) {
    #pragma unroll
    for (int reg = 0; reg < 16; reg++) {
      const int row = (reg & 3) + 8 * (reg >> 2) + 4 * hf;
      #pragma unroll
      for (int ng = 0; ng < 2; ng++)
        Ol[qc][row][ng * 32 + l32] = Oa[ng][reg];
    }
  }
  __syncthreads();
  if (ks == 1) {
    #pragma unroll
    for (int reg = 0; reg < 16; reg++) {
      const int row = (reg & 3) + 8 * (reg >> 2) + 4 * hf;
      const int ql = qc * 32 + row;
      const float rz = 1.f / ((Z1l[ql] + Z1l[64 + ql]) * 4097.f);
      const int s = q0 + ql;
      #pragma unroll
      for (int ng = 0; ng < 2; ng++) {
        const float o = Ol[qc][row][ng * 32 + l32] + Oa[ng][reg];
        OUT[(size_t)s * HID + h * DH + ng * 32 + l32] = f2bf(o * rz);
      }
    }
  }
}

// ----------------------------------------------------------------
extern "C" void kernel_launch(void* const* d_in, const int* in_sizes, int n_in,
                              void* d_out, int out_size, void* d_ws, size_t ws_size,
                              hipStream_t stream) {
  const float* x  = (const float*)d_in[0];
  const float* wq = (const float*)d_in[1];
  const float* bq = (const float*)d_in[2];
  const float* wk = (const float*)d_in[3];
  const float* bk = (const float*)d_in[4];
  const float* wv = (const float*)d_in[5];
  const float* bv = (const float*)d_in[6];
  const float* wo = (const float*)d_in[7];
  const float* bo = (const float*)d_in[8];
  float* out = (float*)d_out;

  char* ws = (char*)d_ws;
  unsigned short* xb  = (unsigned short*)(ws);                 // 8 MB (reused for attn out)
  unsigned short* wqb = (unsigned short*)(ws + (8u  << 20));
  unsigned short* wkb = (unsigned short*)(ws + (10u << 20));
  unsigned short* wvb = (unsigned short*)(ws + (12u << 20));
  unsigned short* wob = (unsigned short*)(ws + (14u << 20));
  unsigned short* qw  = (unsigned short*)(ws + (16u << 20));   // [H][S][64] prescaled
  unsigned short* k2  = (unsigned short*)(ws + (24u << 20));   // frag-packed K (K=16 A-op)
  unsigned short* vb  = (unsigned short*)(ws + (32u << 20));   // frag-packed V (K=8 B-op)
  float* vsump        = (float*)(ws + (40u << 20));            // [8][1024]
  float* be           = (float*)(ws + (40u << 20) + 65536);    // [1024]
  unsigned short* aw  = xb;

  cast_kernel<<<dim3(4096, 5), 256, 0, stream>>>(x, wq, wk, wv, wo, xb, wqb, wkb, wvb, wob);
  qkv_gemm_kernel<<<dim3(32, 8, 3), 256, 0, stream>>>(xb, wqb, wkb, wvb, bq, bk, bv, qw, k2, vb);
  vsum_kernel<<<dim3(8, 16), 256, 0, stream>>>(vb, vsump);
  biasfold_kernel<<<dim3(256), 256, 0, stream>>>(vsump, wo, bo, be);
  attn_kernel<<<dim3(64, 16), 256, 0, stream>>>(qw, k2, vb, aw);
  out_gemm_kernel<<<dim3(32, 8, 1), 256, 0, stream>>>(aw, wob, be, out);
}

// Round 8
// 253.420 us; speedup vs baseline: 1.0523x; 1.0523x over previous
//
#include <hip/hip_runtime.h>
#include <hip/hip_bf16.h>
#include <stdint.h>

#define S 4096
#define HID 1024
#define NH 16
#define DH 64

typedef __attribute__((ext_vector_type(8))) short short8;
typedef __attribute__((ext_vector_type(4))) float f32x4;
typedef __attribute__((ext_vector_type(16))) float f32x16;
typedef __attribute__((ext_vector_type(4))) unsigned int u32x4;

__device__ __forceinline__ unsigned short f2bf(float f) {
  unsigned int u = __builtin_bit_cast(unsigned int, f);
  u += 0x7FFF + ((u >> 16) & 1);   // round-to-nearest-even
  return (unsigned short)(u >> 16);
}
// pack two fp32 -> bf16x2 dword by truncation (1 v_perm_b32)
__device__ __forceinline__ unsigned int pktrunc(float lo, float hi) {
  return __builtin_amdgcn_perm(__builtin_bit_cast(unsigned int, hi),
                               __builtin_bit_cast(unsigned int, lo), 0x07060302u);
}
// async global->LDS, 16B per lane
__device__ __forceinline__ void gload16(const unsigned short* g, unsigned short* l) {
  __builtin_amdgcn_global_load_lds((const __attribute__((address_space(1))) unsigned int*)g,
                                   (__attribute__((address_space(3))) unsigned int*)l, 16, 0, 0);
}

// ---------------------------------------------------------------- cast fp32 -> bf16
__global__ __launch_bounds__(256) void cast_kernel(
    const float* __restrict__ x,  const float* __restrict__ wq,
    const float* __restrict__ wk, const float* __restrict__ wv,
    const float* __restrict__ wo,
    unsigned short* __restrict__ xb,  unsigned short* __restrict__ wqb,
    unsigned short* __restrict__ wkb, unsigned short* __restrict__ wvb,
    unsigned short* __restrict__ wob)
{
  int y = blockIdx.y;
  const float* src; unsigned short* dst; int n;
  if      (y == 0) { src = x;  dst = xb;  n = S * HID; }
  else if (y == 1) { src = wq; dst = wqb; n = HID * HID; }
  else if (y == 2) { src = wk; dst = wkb; n = HID * HID; }
  else if (y == 3) { src = wv; dst = wvb; n = HID * HID; }
  else             { src = wo; dst = wob; n = HID * HID; }
  int i = (blockIdx.x * 256 + threadIdx.x) * 4;
  if (i < n) {
    float4 v = *reinterpret_cast<const float4*>(src + i);
    ushort4 o;
    o.x = f2bf(v.x); o.y = f2bf(v.y); o.z = f2bf(v.z); o.w = f2bf(v.w);
    *reinterpret_cast<ushort4*>(dst + i) = o;
  }
}

// ---------------------------------------------------------------- 128x128 NT GEMM core (m97-style)
__device__ __forceinline__ void gemm128(
    const unsigned short* __restrict__ A, const unsigned short* __restrict__ W,
    unsigned short* As, unsigned short* Bs, f32x4 acc[4][4], int row0, int col0)
{
  const int tid = threadIdx.x;
  const int wave = tid >> 6, lane = tid & 63, quad = lane >> 4, l16 = lane & 15;
  const int wr = (wave >> 1) * 64, wc = (wave & 1) * 64;
  const int srow = lane >> 2, sseg = lane & 3;
  const f32x4 z = {0.f, 0.f, 0.f, 0.f};
  #pragma unroll
  for (int i = 0; i < 4; i++)
    #pragma unroll
    for (int j = 0; j < 4; j++) acc[i][j] = z;

  for (int k0 = 0; k0 < HID; k0 += 32) {
    __syncthreads();
    #pragma unroll
    for (int c = 0; c < 2; c++) {
      const int rbase = c * 64 + wave * 16;
      gload16(A + (size_t)(row0 + rbase + srow) * HID + k0 + sseg * 8, As + rbase * 32);
      gload16(W + (size_t)(col0 + rbase + srow) * HID + k0 + sseg * 8, Bs + rbase * 32);
    }
    __syncthreads();

    short8 af[4], bfr[4];
    #pragma unroll
    for (int i = 0; i < 4; i++)
      af[i] = *reinterpret_cast<const short8*>(As + (wr + i * 16 + l16) * 32 + quad * 8);
    #pragma unroll
    for (int j = 0; j < 4; j++)
      bfr[j] = *reinterpret_cast<const short8*>(Bs + (wc + j * 16 + l16) * 32 + quad * 8);
    #pragma unroll
    for (int i = 0; i < 4; i++)
      #pragma unroll
      for (int j = 0; j < 4; j++)
        acc[i][j] = __builtin_amdgcn_mfma_f32_16x16x32_bf16(af[i], bfr[j], acc[i][j], 0, 0, 0);
  }
}

// QKV projections. Q -> [H][S][64] prescaled by log2e/8.
// K -> K2 frag-packed (K=16 A-op): K2[(((h*128+g)*4+c)*64 + lane)*8 + j]
// V -> Vb frag-packed (K=16 B-op with keys bitswap23-relabeled):
//      Vb[((((h*128+gt)*2+grp)*2+ng)*64 + hf*32 + l32)*8 + j]
//      holds V[key = gt*32+grp*16+bitswap23(hf*8+j)][d = ng*32+l32]
//      so that the S^T C-layout reg-octet IS a valid K=16 PV A-operand.
__global__ __launch_bounds__(256) void qkv_gemm_kernel(
    const unsigned short* __restrict__ X,
    const unsigned short* __restrict__ Wq, const unsigned short* __restrict__ Wk,
    const unsigned short* __restrict__ Wv,
    const float* __restrict__ bq, const float* __restrict__ bk, const float* __restrict__ bv,
    unsigned short* __restrict__ Qo, unsigned short* __restrict__ K2o, unsigned short* __restrict__ Vbo)
{
  __shared__ unsigned short As[128 * 32];
  __shared__ unsigned short Bs[128 * 32];
  const int zsel = blockIdx.z;
  const unsigned short* W = (zsel == 0) ? Wq : (zsel == 1) ? Wk : Wv;
  const float* bias        = (zsel == 0) ? bq : (zsel == 1) ? bk : bv;
  const int row0 = blockIdx.x * 128, col0 = blockIdx.y * 128;
  f32x4 acc[4][4];
  gemm128(X, W, As, Bs, acc, row0, col0);

  const int tid = threadIdx.x;
  const int wave = tid >> 6, lane = tid & 63, quad = lane >> 4, l16 = lane & 15;
  const int wr = (wave >> 1) * 64, wc = (wave & 1) * 64;

  if (zsel == 0) {
    const float osc = 0.18033688011112042f;   // log2(e)/8
    #pragma unroll
    for (int j = 0; j < 4; j++) {
      int n = col0 + wc + j * 16 + l16;
      float bb = bias[n];
      int h = n >> 6, d = n & 63;
      #pragma unroll
      for (int i = 0; i < 4; i++)
        #pragma unroll
        for (int rr = 0; rr < 4; rr++) {
          int s = row0 + wr + i * 16 + quad * 4 + rr;
          Qo[(size_t)(h * S + s) * DH + d] = f2bf((acc[i][j][rr] + bb) * osc);
        }
    }
  } else if (zsel == 1) {
    #pragma unroll
    for (int j = 0; j < 4; j++) {
      int n = col0 + wc + j * 16 + l16;
      float bb = bias[n];
      int h = n >> 6, dh = n & 63;
      int c = dh >> 4, hfk = (dh >> 3) & 1, j8 = dh & 7;
      #pragma unroll
      for (int i = 0; i < 4; i++)
        #pragma unroll
        for (int rr = 0; rr < 4; rr++) {
          int s = row0 + wr + i * 16 + quad * 4 + rr;
          int g = s >> 5, l32k = s & 31;
          K2o[((size_t)((h * 128 + g) * 4 + c) * 64 + hfk * 32 + l32k) * 8 + j8] =
              f2bf(acc[i][j][rr] + bb);
        }
    }
  } else {
    // m = key&15 = quad*4+rr -> hf_v = quad&1, j = (quad>>1)*4 + rr, grp = i&1
    #pragma unroll
    for (int j = 0; j < 4; j++) {
      int n = col0 + wc + j * 16 + l16;
      float bb = bias[n];
      int h = n >> 6, dh = n & 63;
      int ng = dh >> 5, l32v = dh & 31;
      int hf_v = quad & 1, jj0 = (quad >> 1) * 4;
      #pragma unroll
      for (int i = 0; i < 4; i++) {
        int gt = (row0 + wr + i * 16) >> 5;
        int grp = i & 1;
        ushort4 pv;
        pv.x = f2bf(acc[i][j][0] + bb); pv.y = f2bf(acc[i][j][1] + bb);
        pv.z = f2bf(acc[i][j][2] + bb); pv.w = f2bf(acc[i][j][3] + bb);
        *reinterpret_cast<ushort4*>(
            Vbo + ((size_t)(((h * 128 + gt) * 2 + grp) * 2 + ng) * 64 + hf_v * 32 + l32v) * 8 + jj0) = pv;
      }
    }
  }
}

// out = A @ W^T + bias_eff
__global__ __launch_bounds__(256) void out_gemm_kernel(
    const unsigned short* __restrict__ A, const unsigned short* __restrict__ W,
    const float* __restrict__ be, float* __restrict__ dst)
{
  __shared__ unsigned short As[128 * 32];
  __shared__ unsigned short Bs[128 * 32];
  const int row0 = blockIdx.x * 128, col0 = blockIdx.y * 128;
  f32x4 acc[4][4];
  gemm128(A, W, As, Bs, acc, row0, col0);

  const int tid = threadIdx.x;
  const int wave = tid >> 6, lane = tid & 63, quad = lane >> 4, l16 = lane & 15;
  const int wr = (wave >> 1) * 64, wc = (wave & 1) * 64;
  #pragma unroll
  for (int j = 0; j < 4; j++) {
    int n = col0 + wc + j * 16 + l16;
    float bb = be[n];
    #pragma unroll
    for (int i = 0; i < 4; i++)
      #pragma unroll
      for (int rr = 0; rr < 4; rr++) {
        int s = row0 + wr + i * 16 + quad * 4 + rr;
        dst[(size_t)s * HID + n] = acc[i][j][rr] + bb;
      }
  }
}

// VsumP[p][h*64+d] = partial sum of V over gt range (new Vb layout; perm-invariant)
__global__ __launch_bounds__(256) void vsum_kernel(
    const unsigned short* __restrict__ Vb, float* __restrict__ VsumP)
{
  __shared__ float red[256];
  const int p = blockIdx.x, h = blockIdx.y, tid = threadIdx.x;
  const int d = tid & 63, chunk = tid >> 6;
  const int ng = d >> 5, l32 = d & 31;
  float s = 0.f;
  for (int m = 0; m < 4; m++) {
    int gt = p * 16 + chunk * 4 + m;
    #pragma unroll
    for (int grp = 0; grp < 2; grp++)
      #pragma unroll
      for (int hf = 0; hf < 2; hf++) {
        uint4 u = *reinterpret_cast<const uint4*>(
            Vb + ((size_t)(((h * 128 + gt) * 2 + grp) * 2 + ng) * 64 + hf * 32 + l32) * 8);
        const unsigned int w[4] = {u.x, u.y, u.z, u.w};
        #pragma unroll
        for (int q = 0; q < 4; q++) {
          s += __builtin_bit_cast(float, w[q] << 16);
          s += __builtin_bit_cast(float, w[q] & 0xFFFF0000u);
        }
      }
  }
  red[tid] = s;
  __syncthreads();
  if (tid < 64)
    VsumP[p * 1024 + h * 64 + tid] = red[tid] + red[64 + tid] + red[128 + tid] + red[192 + tid];
}

// be[n] = bo[n] + (Vsum . wo[n,:]) / 4097, Vsum = sum of 8 partials
__global__ __launch_bounds__(256) void biasfold_kernel(
    const float* __restrict__ VsumP, const float* __restrict__ wo,
    const float* __restrict__ bo, float* __restrict__ be)
{
  const int n = blockIdx.x * 4 + (threadIdx.x >> 6);
  const int l = threadIdx.x & 63;
  float acc = 0.f;
  #pragma unroll
  for (int i = 0; i < 16; i++) {
    float vs = 0.f;
    #pragma unroll
    for (int p = 0; p < 8; p++) vs += VsumP[p * 1024 + l + 64 * i];
    acc += vs * wo[(size_t)n * HID + l + 64 * i];
  }
  #pragma unroll
  for (int off = 32; off >= 1; off >>= 1) acc += __shfl_xor(acc, off);
  if (l == 0) be[n] = bo[n] + acc * (1.f / 4097.f);
}

// ---------------------------------------------------------------- attention v6
// Collapsed double softmax (w = 1+p): out = (Vsum + softmax1(S)V)/4097.
// PV via FULL-RATE 32x32x16 MFMA: keys are bitswap23-relabeled in Vb so the
// exp'd S^T C-layout reg-octets bit-cast directly into K=16 A-operands.
// Zero cross-lane ops, zero LDS in the loop. One barrier at the end.
__global__ __launch_bounds__(256, 4) void attn_kernel(
    const unsigned short* __restrict__ Q, const unsigned short* __restrict__ K2,
    const unsigned short* __restrict__ Vb, unsigned short* __restrict__ OUT)
{
  __shared__ float Ol[2][32][64];
  __shared__ float Z1l[128];

  const int h = blockIdx.y, q0 = blockIdx.x * 64;
  const int tid = threadIdx.x;
  const int wave = tid >> 6, lane = tid & 63, hf = lane >> 5, l32 = lane & 31;
  const int qc = wave & 1, ks = wave >> 1;

  // Q B-frags (K=16 QK): B[k=c*16+hf*8+j][n=q=l32]
  short8 qf[4];
  {
    const unsigned short* qrow = Q + (size_t)(h * S + q0 + qc * 32 + l32) * DH;
    #pragma unroll
    for (int c = 0; c < 4; c++)
      qf[c] = *reinterpret_cast<const short8*>(qrow + c * 16 + hf * 8);
  }

  float z1p = 0.f;
  f32x16 Oa[2];
  #pragma unroll
  for (int ng = 0; ng < 2; ng++)
    #pragma unroll
    for (int r = 0; r < 16; r++) Oa[ng][r] = 0.f;

  const unsigned short* Kb = K2 + (size_t)h * 128 * 4 * 64 * 8;
  const unsigned short* Vbb = Vb + (size_t)h * 128 * 4 * 64 * 8;

  const int g0 = ks * 64, g1 = g0 + 64;
  for (int g = g0; g < g1; g++) {
    // K A-frags (coalesced dwordx4): A[m=key=l32][k=c*16+hf*8+j]
    short8 kf[4];
    #pragma unroll
    for (int c = 0; c < 4; c++)
      kf[c] = *reinterpret_cast<const short8*>(Kb + ((size_t)(g * 4 + c) * 64 + lane) * 8);
    // V B-frags (K=16, relabeled keys): B[k=hf*8+j][n=d=ng*32+l32]
    short8 vfr[2][2];
    #pragma unroll
    for (int grp = 0; grp < 2; grp++)
      #pragma unroll
      for (int ng = 0; ng < 2; ng++)
        vfr[grp][ng] = *reinterpret_cast<const short8*>(
            Vbb + ((size_t)((g * 2 + grp) * 2 + ng) * 64 + lane) * 8);

    // S^T tile: 32 keys x 32 q (C: col=q=l32, row=key=(reg&3)+4hf+8(reg>>2))
    f32x16 acc;
    #pragma unroll
    for (int r = 0; r < 16; r++) acc[r] = 0.f;
    #pragma unroll
    for (int c = 0; c < 4; c++)
      acc = __builtin_amdgcn_mfma_f32_32x32x16_bf16(kf[c], qf[c], acc, 0, 0, 0);

    // exp + pack: reg-octet [0..7] / [8..15] become K=16 A-operands directly
    unsigned int D[8];
    #pragma unroll
    for (int m = 0; m < 8; m++) {
      float t0 = __builtin_amdgcn_exp2f(acc[2 * m]);
      float t1 = __builtin_amdgcn_exp2f(acc[2 * m + 1]);
      z1p += t0 + t1;
      D[m] = pktrunc(t0, t1);
    }
    u32x4 d0 = {D[0], D[1], D[2], D[3]};
    u32x4 d1 = {D[4], D[5], D[6], D[7]};
    short8 A0 = __builtin_bit_cast(short8, d0);
    short8 A1 = __builtin_bit_cast(short8, d1);

    Oa[0] = __builtin_amdgcn_mfma_f32_32x32x16_bf16(A0, vfr[0][0], Oa[0], 0, 0, 0);
    Oa[1] = __builtin_amdgcn_mfma_f32_32x32x16_bf16(A0, vfr[0][1], Oa[1], 0, 0, 0);
    Oa[0] = __builtin_amdgcn_mfma_f32_32x32x16_bf16(A1, vfr[1][0], Oa[0], 0, 0, 0);
    Oa[1] = __builtin_amdgcn_mfma_f32_32x32x16_bf16(A1, vfr[1][1], Oa[1], 0, 0, 0);
  }

  {
    float z1 = z1p + __shfl_xor(z1p, 32);
    if (hf == 0) Z1l[ks * 64 + qc * 32 + l32] = z1;
  }
  if (ks == 0) {
    #pragma unroll
    for (int reg = 0; reg < 16; reg++) {
      const int row = (reg & 3) + 8 * (reg >> 2) + 4 * hf;
      #pragma unroll
      for (int ng = 0; ng < 2; ng++)
        Ol[qc][row][ng * 32 + l32] = Oa[ng][reg];
    }
  }
  __syncthreads();
  if (ks == 1) {
    #pragma unroll
    for (int reg = 0; reg < 16; reg++) {
      const int row = (reg & 3) + 8 * (reg >> 2) + 4 * hf;
      const int ql = qc * 32 + row;
      const float rz = 1.f / ((Z1l[ql] + Z1l[64 + ql]) * 4097.f);
      const int s = q0 + ql;
      #pragma unroll
      for (int ng = 0; ng < 2; ng++) {
        const float o = Ol[qc][row][ng * 32 + l32] + Oa[ng][reg];
        OUT[(size_t)s * HID + h * DH + ng * 32 + l32] = f2bf(o * rz);
      }
    }
  }
}

// ----------------------------------------------------------------
extern "C" void kernel_launch(void* const* d_in, const int* in_sizes, int n_in,
                              void* d_out, int out_size, void* d_ws, size_t ws_size,
                              hipStream_t stream) {
  const float* x  = (const float*)d_in[0];
  const float* wq = (const float*)d_in[1];
  const float* bq = (const float*)d_in[2];
  const float* wk = (const float*)d_in[3];
  const float* bk = (const float*)d_in[4];
  const float* wv = (const float*)d_in[5];
  const float* bv = (const float*)d_in[6];
  const float* wo = (const float*)d_in[7];
  const float* bo = (const float*)d_in[8];
  float* out = (float*)d_out;

  char* ws = (char*)d_ws;
  unsigned short* xb  = (unsigned short*)(ws);                 // 8 MB (reused for attn out)
  unsigned short* wqb = (unsigned short*)(ws + (8u  << 20));
  unsigned short* wkb = (unsigned short*)(ws + (10u << 20));
  unsigned short* wvb = (unsigned short*)(ws + (12u << 20));
  unsigned short* wob = (unsigned short*)(ws + (14u << 20));
  unsigned short* qw  = (unsigned short*)(ws + (16u << 20));   // [H][S][64] prescaled
  unsigned short* k2  = (unsigned short*)(ws + (24u << 20));   // frag-packed K (K=16 A-op)
  unsigned short* vb  = (unsigned short*)(ws + (32u << 20));   // frag-packed V (K=16 B-op, relabeled)
  float* vsump        = (float*)(ws + (40u << 20));            // [8][1024]
  float* be           = (float*)(ws + (40u << 20) + 65536);    // [1024]
  unsigned short* aw  = xb;

  cast_kernel<<<dim3(4096, 5), 256, 0, stream>>>(x, wq, wk, wv, wo, xb, wqb, wkb, wvb, wob);
  qkv_gemm_kernel<<<dim3(32, 8, 3), 256, 0, stream>>>(xb, wqb, wkb, wvb, bq, bk, bv, qw, k2, vb);
  vsum_kernel<<<dim3(8, 16), 256, 0, stream>>>(vb, vsump);
  biasfold_kernel<<<dim3(256), 256, 0, stream>>>(vsump, wo, bo, be);
  attn_kernel<<<dim3(64, 16), 256, 0, stream>>>(qw, k2, vb, aw);
  out_gemm_kernel<<<dim3(32, 8, 1), 256, 0, stream>>>(aw, wob, be, out);
}